// Round 7
// baseline (477.387 us; speedup 1.0000x reference)
//
#include <hip/hip_runtime.h>
#include <hip/hip_cooperative_groups.h>

namespace cg = cooperative_groups;

// SyntacticGCN on MI355X — fp32 in/out.
// v7: ONE cooperative mega-kernel (grid.sync between phases) replacing the
// 7-dispatch pipeline. Cross-version accounting showed a stable 171-186us
// OUTSIDE the fused kernel (total-fused) while roofline math for those
// kernels sums to ~40-50us -> serialization/bubble overhead of the deep
// pipeline (tiny scan grids, memset, launch/drain x6). Phases:
//   P0 zero counts/bnz | P1 hist+sampler+wconv+conv | P2 chunk scans
//   P3 prefix+cursor | P4 scatter | P5 fused agg+GEMM (v2 structure = the
//   measured-fastest fused: 512thr, 64-row tile, shfl depth-4 pipeline).
// Fallback: if cooperative launch fails, run the v6 6-dispatch pipeline.

typedef __attribute__((ext_vector_type(8))) short short8;
typedef __attribute__((ext_vector_type(4))) float floatx4;

#define DIM 128

static __device__ __forceinline__ float bf2f(unsigned int u16bits) {
    unsigned int x = u16bits << 16;
    return __builtin_bit_cast(float, x);
}
static __device__ __forceinline__ unsigned int f2bf(float f) {
    unsigned int x = __builtin_bit_cast(unsigned int, f);
    return (x + 0x7fffu + ((x >> 16) & 1u)) >> 16;
}

// ---------------- gather macros (v2 structure: 32-lane rows, shfl) ---------------
#define G6(idx)                                                                     \
    ({ int p_ = __shfl(mpx, sl0 + (idx), 64);                                       \
       *(const uint2*)(xb + (size_t)((unsigned)p_ & 0xFFFFFu) * DIM + l * 4); })

#define C6(V, jj) do {                                                              \
    int p_ = __shfl(mpx, sl0 + (jj), 64);                                           \
    float g_ = __shfl(mg, sl0 + (jj), 64);                                          \
    int t_ = (int)((unsigned)p_ >> 20);                                             \
    float x0_ = bf2f((V).x & 0xffffu) * g_;                                         \
    float x1_ = bf2f((V).x >> 16)     * g_;                                         \
    float x2_ = bf2f((V).y & 0xffffu) * g_;                                         \
    float x3_ = bf2f((V).y >> 16)     * g_;                                         \
    if (t_ == 0)      { a00 += x0_; a01 += x1_; a02 += x2_; a03 += x3_; }           \
    else if (t_ == 1) { a10 += x0_; a11 += x1_; a12 += x2_; a13 += x3_; }           \
    else if (t_ == 2) { a20 += x0_; a21 += x1_; a22 += x2_; a23 += x3_; }           \
    else              { a30 += x0_; a31 += x1_; a32 += x2_; a33 += x3_; }           \
} while (0)

// ================================ MEGA KERNEL ====================================
__global__ __launch_bounds__(512, 4) void mega_k(
    const float* __restrict__ inp,
    const float* __restrict__ gin,  const float* __restrict__ gout,
    const float* __restrict__ gself, const float* __restrict__ gnorel,
    const float* __restrict__ Vin, const float* __restrict__ Vout,
    const float* __restrict__ Wself, const float* __restrict__ Wnorel,
    const int* __restrict__ ei, const int* __restrict__ deprel,
    const int* __restrict__ deparc,
    const float* __restrict__ b_in, const float* __restrict__ b_out,
    const float* __restrict__ bg_in, const float* __restrict__ bg_out,
    unsigned short* __restrict__ xb, float* __restrict__ xg,
    unsigned short* __restrict__ wcatT,
    int* __restrict__ counts, int* __restrict__ row_start,
    int* __restrict__ cursor, int* __restrict__ blocksums,
    int2* __restrict__ pe2, int* __restrict__ rel_arr,
    int* __restrict__ bnz, float* __restrict__ Sb, float* __restrict__ out,
    long long nbe, int N, int E)
{
    cg::grid_group grid = cg::this_grid();
    __shared__ __align__(16) unsigned char smem[64 * 1024];
    int* sdata = (int*)smem;

    int tid  = threadIdx.x;
    int gtid = blockIdx.x * 512 + tid;
    int gsz  = gridDim.x * 512;
    int lane = tid & 63;
    int wave = tid >> 6;              // 0..7

    // ---------------- P0: zero counts + bnz ----------------
    for (int i = gtid; i < N; i += gsz) counts[i] = 0;
    if (gtid == 0) *bnz = 0;
    grid.sync();

    // ---------------- P1: hist | sampler | wconv | conv ----------------
    for (int e = gtid; e < E; e += gsz) atomicAdd(&counts[ei[E + e]], 1);
    if (gtid < 65536) {
        long long i = (long long)gtid * (nbe / 65536);
        if (i < nbe && (b_in[i] != 0.f || b_out[i] != 0.f)) *bnz = 1;
    }
    if (gtid < 32768) {       // wcatT[c][k] = bf16(W_t[d][c]), k = t*128+d
        int k = gtid >> 6, c2 = (gtid & 63) * 2;
        int t = k >> 7, d = k & 127;
        const float* Wt = (t == 0) ? Vin : (t == 1) ? Vout : (t == 2) ? Wself : Wnorel;
        float2 w = *(const float2*)(Wt + (size_t)d * DIM + c2);
        wcatT[(size_t)c2 * 512 + k]       = (unsigned short)f2bf(w.x);
        wcatT[(size_t)(c2 + 1) * 512 + k] = (unsigned short)f2bf(w.y);
    }
    {   // conv: 16 nodes/wave; lane(q,l15): node=l15, cols kt*32+q*8..+8
        int q = lane >> 4, l15 = lane & 15;
        int wgid = gtid >> 6;
        int nwav = gsz >> 6;
        for (int base = wgid * 16; base < N; base += nwav * 16) {
            int n = base + l15;
            int rowc = n < N ? n : N - 1;
            const float* xr = inp + (size_t)rowc * DIM;
            float4 acc = make_float4(0.f, 0.f, 0.f, 0.f);
            unsigned xpk[16];
#pragma unroll
            for (int kt = 0; kt < 4; ++kt) {
                int ko = kt * 32 + q * 8;
                float4 xa = *(const float4*)(xr + ko);
                float4 xc = *(const float4*)(xr + ko + 4);
                float4 ga, gb;
                ga = *(const float4*)(gin + ko);    gb = *(const float4*)(gin + ko + 4);
                acc.x += xa.x*ga.x + xa.y*ga.y + xa.z*ga.z + xa.w*ga.w
                       + xc.x*gb.x + xc.y*gb.y + xc.z*gb.z + xc.w*gb.w;
                ga = *(const float4*)(gout + ko);   gb = *(const float4*)(gout + ko + 4);
                acc.y += xa.x*ga.x + xa.y*ga.y + xa.z*ga.z + xa.w*ga.w
                       + xc.x*gb.x + xc.y*gb.y + xc.z*gb.z + xc.w*gb.w;
                ga = *(const float4*)(gself + ko);  gb = *(const float4*)(gself + ko + 4);
                acc.z += xa.x*ga.x + xa.y*ga.y + xa.z*ga.z + xa.w*ga.w
                       + xc.x*gb.x + xc.y*gb.y + xc.z*gb.z + xc.w*gb.w;
                ga = *(const float4*)(gnorel + ko); gb = *(const float4*)(gnorel + ko + 4);
                acc.w += xa.x*ga.x + xa.y*ga.y + xa.z*ga.z + xa.w*ga.w
                       + xc.x*gb.x + xc.y*gb.y + xc.z*gb.z + xc.w*gb.w;
                xpk[kt*4+0] = f2bf(xa.x) | (f2bf(xa.y) << 16);
                xpk[kt*4+1] = f2bf(xa.z) | (f2bf(xa.w) << 16);
                xpk[kt*4+2] = f2bf(xc.x) | (f2bf(xc.y) << 16);
                xpk[kt*4+3] = f2bf(xc.z) | (f2bf(xc.w) << 16);
            }
            if (n < N) {
#pragma unroll
                for (int kt = 0; kt < 4; ++kt) {
                    uint4 o = make_uint4(xpk[kt*4], xpk[kt*4+1], xpk[kt*4+2], xpk[kt*4+3]);
                    *(uint4*)(xb + (size_t)n * DIM + kt * 32 + q * 8) = o;
                }
            }
#pragma unroll
            for (int off = 16; off < 64; off <<= 1) {
                acc.x += __shfl_xor(acc.x, off, 64);
                acc.y += __shfl_xor(acc.y, off, 64);
                acc.z += __shfl_xor(acc.z, off, 64);
                acc.w += __shfl_xor(acc.w, off, 64);
            }
            if (q == 0 && n < N) *(float4*)(xg + (size_t)n * 4) = acc;
        }
    }
    grid.sync();

    // ---------------- P2: per-1024-chunk exclusive scans ----------------
    int nch = (N + 1023) >> 10;
    for (int c = blockIdx.x; c < nch; c += gridDim.x) {
        int idx = c * 1024 + tid * 2;
        int v0 = idx < N ? counts[idx] : 0;
        int v1 = idx + 1 < N ? counts[idx + 1] : 0;
        int s = v0 + v1;
        sdata[tid] = s;
        __syncthreads();
        for (int off = 1; off < 512; off <<= 1) {
            int t = (tid >= off) ? sdata[tid - off] : 0;
            __syncthreads();
            sdata[tid] += t;
            __syncthreads();
        }
        int run = sdata[tid] - s;
        if (idx < N)     row_start[idx]     = run;
        if (idx + 1 < N) row_start[idx + 1] = run + v0;
        if (tid == 511) blocksums[c] = sdata[511];
        __syncthreads();
    }
    grid.sync();

    // ---------------- P3: inline blocksum prefix + cursor ----------------
    for (int c = blockIdx.x; c < nch; c += gridDim.x) {
        if (tid < 128) {
            int v = (tid < c && tid < nch) ? blocksums[tid] : 0;
#pragma unroll
            for (int o = 1; o < 64; o <<= 1) v += __shfl_xor(v, o, 64);
            if ((tid & 63) == 0) sdata[tid >> 6] = v;
        }
        __syncthreads();
        int off = sdata[0] + sdata[1];
        __syncthreads();
        int idx = c * 1024 + tid * 2;
        if (idx < N)     { int v = row_start[idx]     + off; row_start[idx]     = v; cursor[idx]     = v; }
        if (idx + 1 < N) { int v = row_start[idx + 1] + off; row_start[idx + 1] = v; cursor[idx + 1] = v; }
        __syncthreads();
    }
    grid.sync();

    // ---------------- P4: scatter (CSR fill + gate) ----------------
    {
        int bnzv = *bnz;
        for (int e = gtid; e < E; e += gsz) {
            int tgt = ei[E + e];
            int src = ei[e];
            int t   = deparc[e];
            int rel = deprel[e];
            int pos = atomicAdd(&cursor[tgt], 1);
            float gl = xg[(size_t)src * 4 + t];
            if (t == 0)      gl += bg_in[rel];
            else if (t == 1) gl += bg_out[rel];
            float g = 1.f / (1.f + __expf(-gl));
            pe2[pos] = make_int2(src | (t << 20), __builtin_bit_cast(int, g));
            if (bnzv != 0) rel_arr[pos] = rel;
        }
    }
    grid.sync();

    // ---------------- P5: fused aggregate(S) + GEMM + residual + relu -----------
    {
        int bz = (*bnz == 0);
        int half = lane >> 5, l = lane & 31;
        int quad = lane >> 4, l15 = lane & 15;
        int ntile = (N + 63) >> 6;
        for (int tile = blockIdx.x; tile < ntile; tile += gridDim.x) {
            int rowb = tile * 64;
            // phase 1: gather-aggregate S into LDS (v2 structure)
            for (int pass = 0; pass < 4; ++pass) {
                int r = pass * 16 + wave * 2 + half;   // 0..63
                int n = rowb + r;
                bool valid = n < N;
                int start = 0, cnt = 0;
                if (valid) { start = row_start[n]; cnt = counts[n]; }

                float a00=0.f,a01=0.f,a02=0.f,a03=0.f;
                float a10=0.f,a11=0.f,a12=0.f,a13=0.f;
                float a20=0.f,a21=0.f,a22=0.f,a23=0.f;
                float a30=0.f,a31=0.f,a32=0.f,a33=0.f;
                float ab0=0.f,ab1=0.f,ab2=0.f,ab3=0.f;

                if (bz) {
                    for (int b2 = 0; b2 < cnt; b2 += 32) {
                        int m = min(cnt - b2, 32);
                        int mpx = 0; float mg = 0.f;
                        if (l < m) {
                            int2 pp = pe2[(size_t)(start + b2) + l];
                            mpx = pp.x; mg = __builtin_bit_cast(float, pp.y);
                        }
                        int sl0 = half * 32;
                        uint2 v0 = make_uint2(0,0), v1 = v0, v2 = v0, v3 = v0;
                        if (0 < m) v0 = G6(0);
                        if (1 < m) v1 = G6(1);
                        if (2 < m) v2 = G6(2);
                        if (3 < m) v3 = G6(3);
                        for (int j = 0; j < m; j += 4) {
                            C6(v0, j);
                            if (j + 4 < m) v0 = G6(j + 4);
                            if (j + 1 < m) {
                                C6(v1, j + 1);
                                if (j + 5 < m) v1 = G6(j + 5);
                            }
                            if (j + 2 < m) {
                                C6(v2, j + 2);
                                if (j + 6 < m) v2 = G6(j + 6);
                            }
                            if (j + 3 < m) {
                                C6(v3, j + 3);
                                if (j + 7 < m) v3 = G6(j + 7);
                            }
                        }
                    }
                } else {
                    for (int b2 = 0; b2 < cnt; b2 += 32) {
                        int m = min(cnt - b2, 32);
                        int mpx = 0, mrl = 0; float mg = 0.f;
                        if (l < m) {
                            int2 pp = pe2[(size_t)(start + b2) + l];
                            mpx = pp.x; mg = __builtin_bit_cast(float, pp.y);
                            mrl = rel_arr[(size_t)(start + b2) + l];
                        }
                        int sl0 = half * 32;
                        for (int j = 0; j < m; ++j) {
                            int p_ = __shfl(mpx, sl0 + j, 64);
                            float g_ = __shfl(mg, sl0 + j, 64);
                            int rl_ = __shfl(mrl, sl0 + j, 64);
                            int t_ = (int)((unsigned)p_ >> 20);
                            uint2 v = *(const uint2*)(xb + (size_t)((unsigned)p_ & 0xFFFFFu) * DIM + l * 4);
                            float x0_ = bf2f(v.x & 0xffffu) * g_;
                            float x1_ = bf2f(v.x >> 16)     * g_;
                            float x2_ = bf2f(v.y & 0xffffu) * g_;
                            float x3_ = bf2f(v.y >> 16)     * g_;
                            if (t_ == 0) {
                                a00 += x0_; a01 += x1_; a02 += x2_; a03 += x3_;
                                float4 bb = *(const float4*)(b_in + (size_t)rl_ * DIM + l * 4);
                                ab0 += g_*bb.x; ab1 += g_*bb.y; ab2 += g_*bb.z; ab3 += g_*bb.w;
                            } else if (t_ == 1) {
                                a10 += x0_; a11 += x1_; a12 += x2_; a13 += x3_;
                                float4 bb = *(const float4*)(b_out + (size_t)rl_ * DIM + l * 4);
                                ab0 += g_*bb.x; ab1 += g_*bb.y; ab2 += g_*bb.z; ab3 += g_*bb.w;
                            } else if (t_ == 2) { a20 += x0_; a21 += x1_; a22 += x2_; a23 += x3_; }
                            else                { a30 += x0_; a31 += x1_; a32 += x2_; a33 += x3_; }
                        }
                    }
                }

                if (valid) {
                    unsigned sw = (unsigned)((r & 7) << 4);
                    unsigned rb = (unsigned)r * 1024;
                    *(uint2*)(&smem[rb + ((  0u + l * 8u) ^ sw)]) =
                        make_uint2(f2bf(a00) | (f2bf(a01) << 16), f2bf(a02) | (f2bf(a03) << 16));
                    *(uint2*)(&smem[rb + ((256u + l * 8u) ^ sw)]) =
                        make_uint2(f2bf(a10) | (f2bf(a11) << 16), f2bf(a12) | (f2bf(a13) << 16));
                    *(uint2*)(&smem[rb + ((512u + l * 8u) ^ sw)]) =
                        make_uint2(f2bf(a20) | (f2bf(a21) << 16), f2bf(a22) | (f2bf(a23) << 16));
                    *(uint2*)(&smem[rb + ((768u + l * 8u) ^ sw)]) =
                        make_uint2(f2bf(a30) | (f2bf(a31) << 16), f2bf(a32) | (f2bf(a33) << 16));
                    if (!bz)
                        *(float4*)(Sb + (size_t)n * DIM + l * 4) =
                            make_float4(ab0, ab1, ab2, ab3);
                }
            }
            __syncthreads();

            // phase 2: S_tile @ Wcat (K=512), 8 waves x 16 cols, 4 row-groups
            int colb = wave * 16 + quad * 4;
            const unsigned short* wc = wcatT + (size_t)(wave * 16 + l15) * 512;
            floatx4 ac0 = {0.f,0.f,0.f,0.f}, ac1 = ac0, ac2 = ac0, ac3 = ac0;
            unsigned swl = (unsigned)((l15 & 7) << 4);
#pragma unroll
            for (int kt = 0; kt < 16; ++kt) {
                short8 wf = *(const short8*)(wc + kt * 32 + quad * 8);
                unsigned bo = ((unsigned)(kt * 64 + quad * 16)) ^ swl;
                short8 x0 = *(const short8*)(&smem[(unsigned)(     l15) * 1024 + bo]);
                short8 x1 = *(const short8*)(&smem[(unsigned)(16 + l15) * 1024 + bo]);
                short8 x2 = *(const short8*)(&smem[(unsigned)(32 + l15) * 1024 + bo]);
                short8 x3 = *(const short8*)(&smem[(unsigned)(48 + l15) * 1024 + bo]);
                ac0 = __builtin_amdgcn_mfma_f32_16x16x32_bf16(wf, x0, ac0, 0, 0, 0);
                ac1 = __builtin_amdgcn_mfma_f32_16x16x32_bf16(wf, x1, ac1, 0, 0, 0);
                ac2 = __builtin_amdgcn_mfma_f32_16x16x32_bf16(wf, x2, ac2, 0, 0, 0);
                ac3 = __builtin_amdgcn_mfma_f32_16x16x32_bf16(wf, x3, ac3, 0, 0, 0);
            }

#define EPI6(AC, S) do {                                                            \
    int row = rowb + (S) * 16 + l15;                                                \
    if (row < N) {                                                                  \
        uint2 ix = *(const uint2*)(xb + (size_t)row * DIM + colb);                  \
        float4 o;                                                                   \
        o.x = (AC)[0] + bf2f(ix.x & 0xffffu);                                       \
        o.y = (AC)[1] + bf2f(ix.x >> 16);                                           \
        o.z = (AC)[2] + bf2f(ix.y & 0xffffu);                                       \
        o.w = (AC)[3] + bf2f(ix.y >> 16);                                           \
        if (!bz) {                                                                  \
            float4 sb = *(const float4*)(Sb + (size_t)row * DIM + colb);            \
            o.x += sb.x; o.y += sb.y; o.z += sb.z; o.w += sb.w;                     \
        }                                                                           \
        o.x = fmaxf(o.x, 0.f); o.y = fmaxf(o.y, 0.f);                               \
        o.z = fmaxf(o.z, 0.f); o.w = fmaxf(o.w, 0.f);                               \
        *(float4*)(out + (size_t)row * DIM + colb) = o;                             \
    }                                                                               \
} while (0)
            EPI6(ac0, 0);
            EPI6(ac1, 1);
            EPI6(ac2, 2);
            EPI6(ac3, 3);
#undef EPI6
            __syncthreads();
        }
    }
}

// ========================= FALLBACK PIPELINE (v6, unchanged) =====================
__global__ __launch_bounds__(256) void conv_hist_k(
    const float* __restrict__ inp,
    const float* __restrict__ gin,  const float* __restrict__ gout,
    const float* __restrict__ gself, const float* __restrict__ gnorel,
    const float* __restrict__ Vin, const float* __restrict__ Vout,
    const float* __restrict__ Wself, const float* __restrict__ Wnorel,
    unsigned short* __restrict__ xb, float* __restrict__ xg,
    unsigned short* __restrict__ wcatT,
    const int* __restrict__ ei, int* __restrict__ counts,
    const float* __restrict__ b_in, const float* __restrict__ b_out,
    int* __restrict__ bnz, long long nbe,
    int N, int E, int nb_conv, int nb_edge)
{
    int bx = (int)blockIdx.x;
    if (bx >= nb_conv + nb_edge + 256) {
        int gid = (bx - nb_conv - nb_edge - 256) * 256 + threadIdx.x;
        int k = gid >> 6;
        int c2 = (gid & 63) * 2;
        int t = k >> 7, d = k & 127;
        const float* Wt = (t == 0) ? Vin : (t == 1) ? Vout : (t == 2) ? Wself : Wnorel;
        float2 w = *(const float2*)(Wt + (size_t)d * DIM + c2);
        wcatT[(size_t)c2 * 512 + k]       = (unsigned short)f2bf(w.x);
        wcatT[(size_t)(c2 + 1) * 512 + k] = (unsigned short)f2bf(w.y);
        return;
    }
    if (bx >= nb_conv + nb_edge) {
        long long tid = (long long)(bx - nb_conv - nb_edge) * 256 + threadIdx.x;
        long long stride = nbe / 65536;
        long long i = tid * stride;
        if (i < nbe && (b_in[i] != 0.f || b_out[i] != 0.f)) *bnz = 1;
        return;
    }
    if (bx >= nb_conv) {
        int e = (bx - nb_conv) * 256 + threadIdx.x;
        if (e < E) atomicAdd(&counts[ei[E + e]], 1);
        return;
    }
    int wv   = threadIdx.x >> 6;
    int lane = threadIdx.x & 63;
    int q = lane >> 4, l15 = lane & 15;
    int n = bx * 64 + wv * 16 + l15;
    int rowc = n < N ? n : N - 1;
    const float* xr = inp + (size_t)rowc * DIM;

    float4 acc = make_float4(0.f, 0.f, 0.f, 0.f);
    unsigned xpk[16];
#pragma unroll
    for (int kt = 0; kt < 4; ++kt) {
        int ko = kt * 32 + q * 8;
        float4 xa = *(const float4*)(xr + ko);
        float4 xc = *(const float4*)(xr + ko + 4);
        float4 ga, gb;
        ga = *(const float4*)(gin + ko);    gb = *(const float4*)(gin + ko + 4);
        acc.x += xa.x*ga.x + xa.y*ga.y + xa.z*ga.z + xa.w*ga.w
               + xc.x*gb.x + xc.y*gb.y + xc.z*gb.z + xc.w*gb.w;
        ga = *(const float4*)(gout + ko);   gb = *(const float4*)(gout + ko + 4);
        acc.y += xa.x*ga.x + xa.y*ga.y + xa.z*ga.z + xa.w*ga.w
               + xc.x*gb.x + xc.y*gb.y + xc.z*gb.z + xc.w*gb.w;
        ga = *(const float4*)(gself + ko);  gb = *(const float4*)(gself + ko + 4);
        acc.z += xa.x*ga.x + xa.y*ga.y + xa.z*ga.z + xa.w*ga.w
               + xc.x*gb.x + xc.y*gb.y + xc.z*gb.z + xc.w*gb.w;
        ga = *(const float4*)(gnorel + ko); gb = *(const float4*)(gnorel + ko + 4);
        acc.w += xa.x*ga.x + xa.y*ga.y + xa.z*ga.z + xa.w*ga.w
               + xc.x*gb.x + xc.y*gb.y + xc.z*gb.z + xc.w*gb.w;
        xpk[kt*4+0] = f2bf(xa.x) | (f2bf(xa.y) << 16);
        xpk[kt*4+1] = f2bf(xa.z) | (f2bf(xa.w) << 16);
        xpk[kt*4+2] = f2bf(xc.x) | (f2bf(xc.y) << 16);
        xpk[kt*4+3] = f2bf(xc.z) | (f2bf(xc.w) << 16);
    }
    if (n < N) {
#pragma unroll
        for (int kt = 0; kt < 4; ++kt) {
            uint4 o = make_uint4(xpk[kt*4], xpk[kt*4+1], xpk[kt*4+2], xpk[kt*4+3]);
            *(uint4*)(xb + (size_t)n * DIM + kt * 32 + q * 8) = o;
        }
    }
#pragma unroll
    for (int off = 16; off < 64; off <<= 1) {
        acc.x += __shfl_xor(acc.x, off, 64);
        acc.y += __shfl_xor(acc.y, off, 64);
        acc.z += __shfl_xor(acc.z, off, 64);
        acc.w += __shfl_xor(acc.w, off, 64);
    }
    if (q == 0 && n < N) *(float4*)(xg + (size_t)n * 4) = acc;
}

__global__ __launch_bounds__(256) void scan_block_k(
    const int* __restrict__ counts, int* __restrict__ row_start,
    int* __restrict__ blocksums, int n)
{
    __shared__ int sdata[256];
    int tid = threadIdx.x;
    int base = blockIdx.x * 1024 + tid * 4;
    int v[4]; int s = 0;
#pragma unroll
    for (int j = 0; j < 4; ++j) {
        v[j] = (base + j < n) ? counts[base + j] : 0;
        s += v[j];
    }
    sdata[tid] = s;
    __syncthreads();
    for (int off = 1; off < 256; off <<= 1) {
        int t = (tid >= off) ? sdata[tid - off] : 0;
        __syncthreads();
        sdata[tid] += t;
        __syncthreads();
    }
    int run = sdata[tid] - s;
#pragma unroll
    for (int j = 0; j < 4; ++j) {
        if (base + j < n) row_start[base + j] = run;
        run += v[j];
    }
    if (tid == 255) blocksums[blockIdx.x] = sdata[255];
}

__global__ __launch_bounds__(256) void scan_add_k(
    int* __restrict__ row_start, int* __restrict__ cursor,
    const int* __restrict__ blocksums, int n, int nb)
{
    __shared__ int red[2];
    int tid = threadIdx.x;
    if (tid < 128) {
        int v = (tid < (int)blockIdx.x && tid < nb) ? blocksums[tid] : 0;
#pragma unroll
        for (int o = 1; o < 64; o <<= 1) v += __shfl_xor(v, o, 64);
        if ((tid & 63) == 0) red[tid >> 6] = v;
    }
    __syncthreads();
    int off = red[0] + red[1];

    int base = blockIdx.x * 1024 + tid * 4;
#pragma unroll
    for (int j = 0; j < 4; ++j) {
        int idx = base + j;
        if (idx < n) {
            int v = row_start[idx] + off;
            row_start[idx] = v;
            cursor[idx] = v;
        }
    }
}

__global__ void scatter_payload_k(
    const int* __restrict__ ei, const int* __restrict__ deprel,
    const int* __restrict__ deparc, int* __restrict__ cursor,
    const float* __restrict__ xg,
    const float* __restrict__ bg_in, const float* __restrict__ bg_out,
    int2* __restrict__ pe2, int* __restrict__ rel_arr,
    const int* __restrict__ bnz, int E)
{
    int e = blockIdx.x * 256 + threadIdx.x;
    if (e >= E) return;
    int tgt = ei[E + e];
    int src = ei[e];
    int t   = deparc[e];
    int rel = deprel[e];
    int pos = atomicAdd(&cursor[tgt], 1);
    float gl = xg[(size_t)src * 4 + t];
    if (t == 0)      gl += bg_in[rel];
    else if (t == 1) gl += bg_out[rel];
    float g = 1.f / (1.f + __expf(-gl));
    pe2[pos] = make_int2(src | (t << 20), __builtin_bit_cast(int, g));
    if (*bnz != 0) rel_arr[pos] = rel;
}

__global__ __launch_bounds__(512, 4) void fused_agg_gemm_k(
    const unsigned short* __restrict__ xb,
    const unsigned short* __restrict__ wcatT,
    const int2* __restrict__ pe2, const int* __restrict__ rel_arr,
    const int* __restrict__ row_start, const int* __restrict__ counts,
    const float* __restrict__ b_in, const float* __restrict__ b_out,
    float* __restrict__ Sb, float* __restrict__ out,
    const int* __restrict__ bnz, int N)
{
    __shared__ __align__(16) unsigned char smem[64 * 1024];
    int tid  = threadIdx.x;
    int wave = tid >> 6, lane = tid & 63;
    int half = lane >> 5, l = lane & 31;
    int quad = lane >> 4, l15 = lane & 15;
    int rowb = blockIdx.x * 64;
    int bz = (*bnz == 0);

    for (int pass = 0; pass < 4; ++pass) {
        int r = pass * 16 + wave * 2 + half;
        int n = rowb + r;
        bool valid = n < N;
        int start = 0, cnt = 0;
        if (valid) { start = row_start[n]; cnt = counts[n]; }

        float a00=0.f,a01=0.f,a02=0.f,a03=0.f;
        float a10=0.f,a11=0.f,a12=0.f,a13=0.f;
        float a20=0.f,a21=0.f,a22=0.f,a23=0.f;
        float a30=0.f,a31=0.f,a32=0.f,a33=0.f;
        float ab0=0.f,ab1=0.f,ab2=0.f,ab3=0.f;

        if (bz) {
            for (int b2 = 0; b2 < cnt; b2 += 32) {
                int m = min(cnt - b2, 32);
                int mpx = 0; float mg = 0.f;
                if (l < m) {
                    int2 pp = pe2[(size_t)(start + b2) + l];
                    mpx = pp.x; mg = __builtin_bit_cast(float, pp.y);
                }
                int sl0 = half * 32;
                uint2 v0 = make_uint2(0,0), v1 = v0, v2 = v0, v3 = v0;
                if (0 < m) v0 = G6(0);
                if (1 < m) v1 = G6(1);
                if (2 < m) v2 = G6(2);
                if (3 < m) v3 = G6(3);
                for (int j = 0; j < m; j += 4) {
                    C6(v0, j);
                    if (j + 4 < m) v0 = G6(j + 4);
                    if (j + 1 < m) { C6(v1, j + 1); if (j + 5 < m) v1 = G6(j + 5); }
                    if (j + 2 < m) { C6(v2, j + 2); if (j + 6 < m) v2 = G6(j + 6); }
                    if (j + 3 < m) { C6(v3, j + 3); if (j + 7 < m) v3 = G6(j + 7); }
                }
            }
        } else {
            for (int b2 = 0; b2 < cnt; b2 += 32) {
                int m = min(cnt - b2, 32);
                int mpx = 0, mrl = 0; float mg = 0.f;
                if (l < m) {
                    int2 pp = pe2[(size_t)(start + b2) + l];
                    mpx = pp.x; mg = __builtin_bit_cast(float, pp.y);
                    mrl = rel_arr[(size_t)(start + b2) + l];
                }
                int sl0 = half * 32;
                for (int j = 0; j < m; ++j) {
                    int p_ = __shfl(mpx, sl0 + j, 64);
                    float g_ = __shfl(mg, sl0 + j, 64);
                    int rl_ = __shfl(mrl, sl0 + j, 64);
                    int t_ = (int)((unsigned)p_ >> 20);
                    uint2 v = *(const uint2*)(xb + (size_t)((unsigned)p_ & 0xFFFFFu) * DIM + l * 4);
                    float x0_ = bf2f(v.x & 0xffffu) * g_;
                    float x1_ = bf2f(v.x >> 16)     * g_;
                    float x2_ = bf2f(v.y & 0xffffu) * g_;
                    float x3_ = bf2f(v.y >> 16)     * g_;
                    if (t_ == 0) {
                        a00 += x0_; a01 += x1_; a02 += x2_; a03 += x3_;
                        float4 bb = *(const float4*)(b_in + (size_t)rl_ * DIM + l * 4);
                        ab0 += g_*bb.x; ab1 += g_*bb.y; ab2 += g_*bb.z; ab3 += g_*bb.w;
                    } else if (t_ == 1) {
                        a10 += x0_; a11 += x1_; a12 += x2_; a13 += x3_;
                        float4 bb = *(const float4*)(b_out + (size_t)rl_ * DIM + l * 4);
                        ab0 += g_*bb.x; ab1 += g_*bb.y; ab2 += g_*bb.z; ab3 += g_*bb.w;
                    } else if (t_ == 2) { a20 += x0_; a21 += x1_; a22 += x2_; a23 += x3_; }
                    else                { a30 += x0_; a31 += x1_; a32 += x2_; a33 += x3_; }
                }
            }
        }

        if (valid) {
            unsigned sw = (unsigned)((r & 7) << 4);
            unsigned rb = (unsigned)r * 1024;
            *(uint2*)(&smem[rb + ((  0u + l * 8u) ^ sw)]) =
                make_uint2(f2bf(a00) | (f2bf(a01) << 16), f2bf(a02) | (f2bf(a03) << 16));
            *(uint2*)(&smem[rb + ((256u + l * 8u) ^ sw)]) =
                make_uint2(f2bf(a10) | (f2bf(a11) << 16), f2bf(a12) | (f2bf(a13) << 16));
            *(uint2*)(&smem[rb + ((512u + l * 8u) ^ sw)]) =
                make_uint2(f2bf(a20) | (f2bf(a21) << 16), f2bf(a22) | (f2bf(a23) << 16));
            *(uint2*)(&smem[rb + ((768u + l * 8u) ^ sw)]) =
                make_uint2(f2bf(a30) | (f2bf(a31) << 16), f2bf(a32) | (f2bf(a33) << 16));
            if (!bz)
                *(float4*)(Sb + (size_t)n * DIM + l * 4) = make_float4(ab0, ab1, ab2, ab3);
        }
    }

    __syncthreads();

    int colb = wave * 16 + quad * 4;
    const unsigned short* wc = wcatT + (size_t)(wave * 16 + l15) * 512;
    floatx4 ac0 = {0.f,0.f,0.f,0.f}, ac1 = ac0, ac2 = ac0, ac3 = ac0;
    unsigned swl = (unsigned)((l15 & 7) << 4);
#pragma unroll
    for (int kt = 0; kt < 16; ++kt) {
        short8 wf = *(const short8*)(wc + kt * 32 + quad * 8);
        unsigned bo = ((unsigned)(kt * 64 + quad * 16)) ^ swl;
        short8 x0 = *(const short8*)(&smem[(unsigned)(     l15) * 1024 + bo]);
        short8 x1 = *(const short8*)(&smem[(unsigned)(16 + l15) * 1024 + bo]);
        short8 x2 = *(const short8*)(&smem[(unsigned)(32 + l15) * 1024 + bo]);
        short8 x3 = *(const short8*)(&smem[(unsigned)(48 + l15) * 1024 + bo]);
        ac0 = __builtin_amdgcn_mfma_f32_16x16x32_bf16(wf, x0, ac0, 0, 0, 0);
        ac1 = __builtin_amdgcn_mfma_f32_16x16x32_bf16(wf, x1, ac1, 0, 0, 0);
        ac2 = __builtin_amdgcn_mfma_f32_16x16x32_bf16(wf, x2, ac2, 0, 0, 0);
        ac3 = __builtin_amdgcn_mfma_f32_16x16x32_bf16(wf, x3, ac3, 0, 0, 0);
    }

#define EPI(AC, S) do {                                                             \
    int row = rowb + (S) * 16 + l15;                                                \
    if (row < N) {                                                                  \
        uint2 ix = *(const uint2*)(xb + (size_t)row * DIM + colb);                  \
        float4 o;                                                                   \
        o.x = (AC)[0] + bf2f(ix.x & 0xffffu);                                       \
        o.y = (AC)[1] + bf2f(ix.x >> 16);                                           \
        o.z = (AC)[2] + bf2f(ix.y & 0xffffu);                                       \
        o.w = (AC)[3] + bf2f(ix.y >> 16);                                           \
        if (!bz) {                                                                  \
            float4 sb = *(const float4*)(Sb + (size_t)row * DIM + colb);            \
            o.x += sb.x; o.y += sb.y; o.z += sb.z; o.w += sb.w;                     \
        }                                                                           \
        o.x = fmaxf(o.x, 0.f); o.y = fmaxf(o.y, 0.f);                               \
        o.z = fmaxf(o.z, 0.f); o.w = fmaxf(o.w, 0.f);                               \
        *(float4*)(out + (size_t)row * DIM + colb) = o;                             \
    }                                                                               \
} while (0)

    EPI(ac0, 0);
    EPI(ac1, 1);
    EPI(ac2, 2);
    EPI(ac3, 3);
#undef EPI
}

// ================================== LAUNCH =======================================
extern "C" void kernel_launch(void* const* d_in, const int* in_sizes, int n_in,
                              void* d_out, int out_size, void* d_ws, size_t ws_size,
                              hipStream_t stream)
{
    const float* inp    = (const float*)d_in[0];
    const int*   deprel = (const int*)d_in[1];
    const int*   deparc = (const int*)d_in[2];
    const int*   ei     = (const int*)d_in[3];
    const float* Vin    = (const float*)d_in[4];
    const float* b_in   = (const float*)d_in[5];
    const float* gin    = (const float*)d_in[6];
    const float* bg_in  = (const float*)d_in[7];
    const float* Vout   = (const float*)d_in[8];
    const float* b_out  = (const float*)d_in[9];
    const float* gout   = (const float*)d_in[10];
    const float* bg_out = (const float*)d_in[11];
    const float* Wself  = (const float*)d_in[12];
    const float* gself  = (const float*)d_in[13];
    const float* Wnorel = (const float*)d_in[14];
    const float* gnorel = (const float*)d_in[15];
    float*       out    = (float*)d_out;

    int N = in_sizes[0] / DIM;   // 100000
    int E = in_sizes[1];         // 400000
    long long nbe = (long long)in_sizes[5];  // R*128

    char* ws = (char*)d_ws;
    size_t off = 0;
    auto alloc = [&](size_t bytes) -> void* {
        void* p = ws + off;
        off = (off + bytes + 255) & ~(size_t)255;
        return p;
    };
    float*          xg        = (float*)alloc((size_t)N * 4 * 4);
    int*            counts    = (int*)alloc((size_t)N * 4);   // |
    int*            bnz       = (int*)alloc(256);             // | one memset region
    int*            row_start = (int*)alloc((size_t)N * 4);
    int*            cursor    = (int*)alloc((size_t)N * 4);
    int2*           pe2       = (int2*)alloc((size_t)E * 8);
    int*            rel_arr   = (int*)alloc((size_t)E * 4);
    int*            blocksums = (int*)alloc(128 * 4);
    unsigned short* xb        = (unsigned short*)alloc((size_t)N * DIM * 2); // 25.6 MB
    unsigned short* wcatT     = (unsigned short*)alloc((size_t)128 * 512 * 2); // 128 KB
    float*          Sb        = (float*)alloc((size_t)N * DIM * 4);          // 51.2 MB

    // -------- try the single cooperative mega-kernel --------
    int maxb = 0;
    hipError_t oe = hipOccupancyMaxActiveBlocksPerMultiprocessor(&maxb, mega_k, 512, 0);
    if (oe == hipSuccess && maxb >= 1) {
        int grid = maxb * 256;               // 256 CUs on MI355X
        if (grid > 1024) grid = 1024;
        void* args[] = {
            (void*)&inp, (void*)&gin, (void*)&gout, (void*)&gself, (void*)&gnorel,
            (void*)&Vin, (void*)&Vout, (void*)&Wself, (void*)&Wnorel,
            (void*)&ei, (void*)&deprel, (void*)&deparc,
            (void*)&b_in, (void*)&b_out, (void*)&bg_in, (void*)&bg_out,
            (void*)&xb, (void*)&xg, (void*)&wcatT,
            (void*)&counts, (void*)&row_start, (void*)&cursor, (void*)&blocksums,
            (void*)&pe2, (void*)&rel_arr, (void*)&bnz, (void*)&Sb, (void*)&out,
            (void*)&nbe, (void*)&N, (void*)&E
        };
        hipError_t le = hipLaunchCooperativeKernel((void*)mega_k, dim3(grid), dim3(512),
                                                   args, 0, stream);
        if (le == hipSuccess) return;
    }

    // -------- fallback: v6 6-dispatch pipeline --------
    int nb_scan  = (N + 1023) / 1024;
    int nb_edge  = (E + 255) / 256;
    int nb_node  = (N + 63) / 64;
    int nb_fused = (N + 63) / 64;

    size_t zlen = (size_t)((char*)bnz - (char*)counts) + 256;
    hipMemsetAsync(counts, 0, zlen, stream);

    conv_hist_k<<<nb_node + nb_edge + 256 + 128, 256, 0, stream>>>(
        inp, gin, gout, gself, gnorel, Vin, Vout, Wself, Wnorel,
        xb, xg, wcatT, ei, counts, b_in, b_out, bnz, nbe, N, E, nb_node, nb_edge);

    scan_block_k<<<nb_scan, 256, 0, stream>>>(counts, row_start, blocksums, N);
    scan_add_k<<<nb_scan, 256, 0, stream>>>(row_start, cursor, blocksums, N, nb_scan);
    scatter_payload_k<<<nb_edge, 256, 0, stream>>>(ei, deprel, deparc, cursor,
                                                   xg, bg_in, bg_out, pe2, rel_arr, bnz, E);

    fused_agg_gemm_k<<<nb_fused, 512, 0, stream>>>(
        xb, wcatT, pe2, rel_arr, row_start, counts, b_in, b_out, Sb, out, bnz, N);
}

// Round 8
// 256.081 us; speedup vs baseline: 1.8642x; 1.8642x over previous
//
#include <hip/hip_runtime.h>

// SyntacticGCN on MI355X — fp32 in/out.
// v8: 5-dispatch pipeline + proven-best fused (v2 structure).
//   S[n, t*128+d] = sum_{e:tgt=n,t_e=t} g_e * x[src_e, d]   (gather from 25.6MB xb)
//   out[n] = relu(inp[n] + S[n,:] @ Wcat)                    (one K=512 GEMM)
//
// v7 post-mortem: cooperative grid.sync ~60us each on this runtime (mega 440us
// with work-time conserved per VALU/MFMA busy-time accounting) -> coop dead.
// Roofline for non-fused kernels sums to ~45-50us vs measured ~171us "other"
// -> ~20us/dispatch-boundary overhead. v8 levers:
//   - fused reverted to v2 structure (512thr, 64-row tile, 64KB LDS, shfl
//     depth-4 gather pipeline, bounds(512,2)) — the only 80.5us config.
//   - scan_block+scan_add merged into ONE decoupled-lookback kernel (98
//     co-resident blocks; device-scope atomics for cross-XCD flag visibility).
//   - pipeline: memset | conv_hist | scan_1pass | scatter | fused (5 nodes).

typedef __attribute__((ext_vector_type(8))) short short8;
typedef __attribute__((ext_vector_type(4))) float floatx4;

#define DIM 128

static __device__ __forceinline__ float bf2f(unsigned int u16bits) {
    unsigned int x = u16bits << 16;
    return __builtin_bit_cast(float, x);
}
static __device__ __forceinline__ unsigned int f2bf(float f) {
    unsigned int x = __builtin_bit_cast(unsigned int, f);
    return (x + 0x7fffu + ((x >> 16) & 1u)) >> 16;
}

// ------- fused: conv+gate (node blocks) | hist | zcheck | weight-convert ---------
__global__ __launch_bounds__(256) void conv_hist_k(
    const float* __restrict__ inp,
    const float* __restrict__ gin,  const float* __restrict__ gout,
    const float* __restrict__ gself, const float* __restrict__ gnorel,
    const float* __restrict__ Vin, const float* __restrict__ Vout,
    const float* __restrict__ Wself, const float* __restrict__ Wnorel,
    unsigned short* __restrict__ xb, float* __restrict__ xg,
    unsigned short* __restrict__ wcatT,
    const int* __restrict__ ei, int* __restrict__ counts,
    const float* __restrict__ b_in, const float* __restrict__ b_out,
    int* __restrict__ bnz, long long nbe,
    int N, int E, int nb_conv, int nb_edge)
{
    int bx = (int)blockIdx.x;
    if (bx >= nb_conv + nb_edge + 256) {
        // weight convert: wcatT[c][k] = bf16(W_t[d][c]), k = t*128+d. 128 blocks.
        int gid = (bx - nb_conv - nb_edge - 256) * 256 + threadIdx.x; // 32768
        int k = gid >> 6;            // 0..511
        int c2 = (gid & 63) * 2;     // 0,2,..,126
        int t = k >> 7, d = k & 127;
        const float* Wt = (t == 0) ? Vin : (t == 1) ? Vout : (t == 2) ? Wself : Wnorel;
        float2 w = *(const float2*)(Wt + (size_t)d * DIM + c2);
        wcatT[(size_t)c2 * 512 + k]       = (unsigned short)f2bf(w.x);
        wcatT[(size_t)(c2 + 1) * 512 + k] = (unsigned short)f2bf(w.y);
        return;
    }
    if (bx >= nb_conv + nb_edge) {
        // sampler: 256 blocks x 256 threads, strided over the bias tables
        long long tid = (long long)(bx - nb_conv - nb_edge) * 256 + threadIdx.x;
        long long stride = nbe / 65536;
        long long i = tid * stride;
        if (i < nbe && (b_in[i] != 0.f || b_out[i] != 0.f)) *bnz = 1;
        return;
    }
    if (bx >= nb_conv) {
        int e = (bx - nb_conv) * 256 + threadIdx.x;
        if (e < E) atomicAdd(&counts[ei[E + e]], 1);
        return;
    }
    // node-conv: 4 waves x 16 nodes = 64 nodes per block.
    int wv   = threadIdx.x >> 6;
    int lane = threadIdx.x & 63;
    int q = lane >> 4, l15 = lane & 15;
    int n = bx * 64 + wv * 16 + l15;
    int rowc = n < N ? n : N - 1;
    const float* xr = inp + (size_t)rowc * DIM;

    float4 acc = make_float4(0.f, 0.f, 0.f, 0.f);
    unsigned xpk[16];
#pragma unroll
    for (int kt = 0; kt < 4; ++kt) {
        int ko = kt * 32 + q * 8;
        float4 xa = *(const float4*)(xr + ko);
        float4 xc = *(const float4*)(xr + ko + 4);
        float4 ga, gb;
        ga = *(const float4*)(gin + ko);    gb = *(const float4*)(gin + ko + 4);
        acc.x += xa.x*ga.x + xa.y*ga.y + xa.z*ga.z + xa.w*ga.w
               + xc.x*gb.x + xc.y*gb.y + xc.z*gb.z + xc.w*gb.w;
        ga = *(const float4*)(gout + ko);   gb = *(const float4*)(gout + ko + 4);
        acc.y += xa.x*ga.x + xa.y*ga.y + xa.z*ga.z + xa.w*ga.w
               + xc.x*gb.x + xc.y*gb.y + xc.z*gb.z + xc.w*gb.w;
        ga = *(const float4*)(gself + ko);  gb = *(const float4*)(gself + ko + 4);
        acc.z += xa.x*ga.x + xa.y*ga.y + xa.z*ga.z + xa.w*ga.w
               + xc.x*gb.x + xc.y*gb.y + xc.z*gb.z + xc.w*gb.w;
        ga = *(const float4*)(gnorel + ko); gb = *(const float4*)(gnorel + ko + 4);
        acc.w += xa.x*ga.x + xa.y*ga.y + xa.z*ga.z + xa.w*ga.w
               + xc.x*gb.x + xc.y*gb.y + xc.z*gb.z + xc.w*gb.w;
        xpk[kt*4+0] = f2bf(xa.x) | (f2bf(xa.y) << 16);
        xpk[kt*4+1] = f2bf(xa.z) | (f2bf(xa.w) << 16);
        xpk[kt*4+2] = f2bf(xc.x) | (f2bf(xc.y) << 16);
        xpk[kt*4+3] = f2bf(xc.z) | (f2bf(xc.w) << 16);
    }
    if (n < N) {
#pragma unroll
        for (int kt = 0; kt < 4; ++kt) {
            uint4 o = make_uint4(xpk[kt*4], xpk[kt*4+1], xpk[kt*4+2], xpk[kt*4+3]);
            *(uint4*)(xb + (size_t)n * DIM + kt * 32 + q * 8) = o;
        }
    }
#pragma unroll
    for (int off = 16; off < 64; off <<= 1) {
        acc.x += __shfl_xor(acc.x, off, 64);
        acc.y += __shfl_xor(acc.y, off, 64);
        acc.z += __shfl_xor(acc.z, off, 64);
        acc.w += __shfl_xor(acc.w, off, 64);
    }
    if (q == 0 && n < N) *(float4*)(xg + (size_t)n * 4) = acc;
}

// -------- single-pass scan: per-1024-chunk scan + decoupled lookback ------------
// 98 blocks, all co-resident on 256 CUs. Block publishes (total+1) to flags[c]
// via device-scope atomicExch; spins device-scope reads on predecessors.
__global__ __launch_bounds__(256) void scan_onepass_k(
    const int* __restrict__ counts, int* __restrict__ row_start,
    int* __restrict__ cursor, int* __restrict__ flags, int n)
{
    __shared__ int sdata[256];
    __shared__ int red[2];
    int tid = threadIdx.x;
    int base = blockIdx.x * 1024 + tid * 4;
    int v[4]; int s = 0;
#pragma unroll
    for (int j = 0; j < 4; ++j) {
        v[j] = (base + j < n) ? counts[base + j] : 0;
        s += v[j];
    }
    sdata[tid] = s;
    __syncthreads();
    for (int off = 1; off < 256; off <<= 1) {
        int t = (tid >= off) ? sdata[tid - off] : 0;
        __syncthreads();
        sdata[tid] += t;
        __syncthreads();
    }
    // publish block aggregate (nonzero sentinel), device scope
    if (tid == 255) {
        __threadfence();
        atomicExch(&flags[blockIdx.x], sdata[255] + 1);
    }
    // lookback: sum all predecessor aggregates
    if (tid < 128) {
        int pv = 0;
        if (tid < (int)blockIdx.x) {
            int f;
            do { f = atomicAdd(&flags[tid], 0); } while (f == 0);
            pv = f - 1;
        }
#pragma unroll
        for (int o = 1; o < 64; o <<= 1) pv += __shfl_xor(pv, o, 64);
        if ((tid & 63) == 0) red[tid >> 6] = pv;
    }
    __syncthreads();
    int off = red[0] + red[1];
    int run = sdata[tid] - s + off;
#pragma unroll
    for (int j = 0; j < 4; ++j) {
        if (base + j < n) { row_start[base + j] = run; cursor[base + j] = run; }
        run += v[j];
    }
}

// -- fused scatter + gate logit + sigmoid; payload int2 (src|t, gate) -------------
__global__ void scatter_payload_k(
    const int* __restrict__ ei, const int* __restrict__ deprel,
    const int* __restrict__ deparc, int* __restrict__ cursor,
    const float* __restrict__ xg,
    const float* __restrict__ bg_in, const float* __restrict__ bg_out,
    int2* __restrict__ pe2, int* __restrict__ rel_arr,
    const int* __restrict__ bnz, int E)
{
    int e = blockIdx.x * 256 + threadIdx.x;
    if (e >= E) return;
    int tgt = ei[E + e];
    int src = ei[e];
    int t   = deparc[e];
    int rel = deprel[e];
    int pos = atomicAdd(&cursor[tgt], 1);
    float gl = xg[(size_t)src * 4 + t];
    if (t == 0)      gl += bg_in[rel];
    else if (t == 1) gl += bg_out[rel];
    float g = 1.f / (1.f + __expf(-gl));
    pe2[pos] = make_int2(src | (t << 20), __builtin_bit_cast(int, g));
    if (*bnz != 0) rel_arr[pos] = rel;  // bias fallback only
}

// ---------------- fused aggregate(S) + GEMM(K=512) + residual + relu -------------
// v2 structure (measured-best 80.5us): 512 thr, 64-row tile, 2 rows/wave,
// 32-lane rows, shfl depth-4 gather pipeline, 64KB XOR-swizzled LDS S-tile.
#define G6(idx)                                                                     \
    ({ int p_ = __shfl(mpx, sl0 + (idx), 64);                                       \
       *(const uint2*)(xb + (size_t)((unsigned)p_ & 0xFFFFFu) * DIM + l * 4); })

#define C6(V, jj) do {                                                              \
    int p_ = __shfl(mpx, sl0 + (jj), 64);                                           \
    float g_ = __shfl(mg, sl0 + (jj), 64);                                          \
    int t_ = (int)((unsigned)p_ >> 20);                                             \
    float x0_ = bf2f((V).x & 0xffffu) * g_;                                         \
    float x1_ = bf2f((V).x >> 16)     * g_;                                         \
    float x2_ = bf2f((V).y & 0xffffu) * g_;                                         \
    float x3_ = bf2f((V).y >> 16)     * g_;                                         \
    if (t_ == 0)      { a00 += x0_; a01 += x1_; a02 += x2_; a03 += x3_; }           \
    else if (t_ == 1) { a10 += x0_; a11 += x1_; a12 += x2_; a13 += x3_; }           \
    else if (t_ == 2) { a20 += x0_; a21 += x1_; a22 += x2_; a23 += x3_; }           \
    else              { a30 += x0_; a31 += x1_; a32 += x2_; a33 += x3_; }           \
} while (0)

__global__ __launch_bounds__(512, 2) void fused_agg_gemm_k(
    const unsigned short* __restrict__ xb,
    const unsigned short* __restrict__ wcatT,
    const int2* __restrict__ pe2, const int* __restrict__ rel_arr,
    const int* __restrict__ row_start, const int* __restrict__ counts,
    const float* __restrict__ b_in, const float* __restrict__ b_out,
    float* __restrict__ Sb, float* __restrict__ out,
    const int* __restrict__ bnz, int N)
{
    __shared__ __align__(16) unsigned char smem[64 * 1024];
    int tid  = threadIdx.x;
    int wave = tid >> 6, lane = tid & 63;
    int half = lane >> 5, l = lane & 31;
    int quad = lane >> 4, l15 = lane & 15;
    int rowb = blockIdx.x * 64;
    int bz = (*bnz == 0);

    for (int pass = 0; pass < 4; ++pass) {
        int r = pass * 16 + wave * 2 + half;
        int n = rowb + r;
        bool valid = n < N;
        int start = 0, cnt = 0;
        if (valid) { start = row_start[n]; cnt = counts[n]; }

        float a00=0.f,a01=0.f,a02=0.f,a03=0.f;
        float a10=0.f,a11=0.f,a12=0.f,a13=0.f;
        float a20=0.f,a21=0.f,a22=0.f,a23=0.f;
        float a30=0.f,a31=0.f,a32=0.f,a33=0.f;
        float ab0=0.f,ab1=0.f,ab2=0.f,ab3=0.f;

        if (bz) {
            for (int b2 = 0; b2 < cnt; b2 += 32) {
                int m = min(cnt - b2, 32);
                int mpx = 0; float mg = 0.f;
                if (l < m) {
                    int2 pp = pe2[(size_t)(start + b2) + l];
                    mpx = pp.x; mg = __builtin_bit_cast(float, pp.y);
                }
                int sl0 = half * 32;
                uint2 v0 = make_uint2(0,0), v1 = v0, v2 = v0, v3 = v0;
                if (0 < m) v0 = G6(0);
                if (1 < m) v1 = G6(1);
                if (2 < m) v2 = G6(2);
                if (3 < m) v3 = G6(3);
                for (int j = 0; j < m; j += 4) {
                    C6(v0, j);
                    if (j + 4 < m) v0 = G6(j + 4);
                    if (j + 1 < m) { C6(v1, j + 1); if (j + 5 < m) v1 = G6(j + 5); }
                    if (j + 2 < m) { C6(v2, j + 2); if (j + 6 < m) v2 = G6(j + 6); }
                    if (j + 3 < m) { C6(v3, j + 3); if (j + 7 < m) v3 = G6(j + 7); }
                }
            }
        } else {
            for (int b2 = 0; b2 < cnt; b2 += 32) {
                int m = min(cnt - b2, 32);
                int mpx = 0, mrl = 0; float mg = 0.f;
                if (l < m) {
                    int2 pp = pe2[(size_t)(start + b2) + l];
                    mpx = pp.x; mg = __builtin_bit_cast(float, pp.y);
                    mrl = rel_arr[(size_t)(start + b2) + l];
                }
                int sl0 = half * 32;
                for (int j = 0; j < m; ++j) {
                    int p_ = __shfl(mpx, sl0 + j, 64);
                    float g_ = __shfl(mg, sl0 + j, 64);
                    int rl_ = __shfl(mrl, sl0 + j, 64);
                    int t_ = (int)((unsigned)p_ >> 20);
                    uint2 v = *(const uint2*)(xb + (size_t)((unsigned)p_ & 0xFFFFFu) * DIM + l * 4);
                    float x0_ = bf2f(v.x & 0xffffu) * g_;
                    float x1_ = bf2f(v.x >> 16)     * g_;
                    float x2_ = bf2f(v.y & 0xffffu) * g_;
                    float x3_ = bf2f(v.y >> 16)     * g_;
                    if (t_ == 0) {
                        a00 += x0_; a01 += x1_; a02 += x2_; a03 += x3_;
                        float4 bb = *(const float4*)(b_in + (size_t)rl_ * DIM + l * 4);
                        ab0 += g_*bb.x; ab1 += g_*bb.y; ab2 += g_*bb.z; ab3 += g_*bb.w;
                    } else if (t_ == 1) {
                        a10 += x0_; a11 += x1_; a12 += x2_; a13 += x3_;
                        float4 bb = *(const float4*)(b_out + (size_t)rl_ * DIM + l * 4);
                        ab0 += g_*bb.x; ab1 += g_*bb.y; ab2 += g_*bb.z; ab3 += g_*bb.w;
                    } else if (t_ == 2) { a20 += x0_; a21 += x1_; a22 += x2_; a23 += x3_; }
                    else                { a30 += x0_; a31 += x1_; a32 += x2_; a33 += x3_; }
                }
            }
        }

        if (valid) {
            unsigned sw = (unsigned)((r & 7) << 4);
            unsigned rb = (unsigned)r * 1024;
            *(uint2*)(&smem[rb + ((  0u + l * 8u) ^ sw)]) =
                make_uint2(f2bf(a00) | (f2bf(a01) << 16), f2bf(a02) | (f2bf(a03) << 16));
            *(uint2*)(&smem[rb + ((256u + l * 8u) ^ sw)]) =
                make_uint2(f2bf(a10) | (f2bf(a11) << 16), f2bf(a12) | (f2bf(a13) << 16));
            *(uint2*)(&smem[rb + ((512u + l * 8u) ^ sw)]) =
                make_uint2(f2bf(a20) | (f2bf(a21) << 16), f2bf(a22) | (f2bf(a23) << 16));
            *(uint2*)(&smem[rb + ((768u + l * 8u) ^ sw)]) =
                make_uint2(f2bf(a30) | (f2bf(a31) << 16), f2bf(a32) | (f2bf(a33) << 16));
            if (!bz)
                *(float4*)(Sb + (size_t)n * DIM + l * 4) = make_float4(ab0, ab1, ab2, ab3);
        }
    }

    __syncthreads();

    // phase 2: S_tile @ Wcat (K=512), 8 waves x 16 cols, 4 row-groups
    int colb = wave * 16 + quad * 4;
    const unsigned short* wc = wcatT + (size_t)(wave * 16 + l15) * 512;
    floatx4 ac0 = {0.f,0.f,0.f,0.f}, ac1 = ac0, ac2 = ac0, ac3 = ac0;
    unsigned swl = (unsigned)((l15 & 7) << 4);
#pragma unroll
    for (int kt = 0; kt < 16; ++kt) {
        short8 wf = *(const short8*)(wc + kt * 32 + quad * 8);
        unsigned bo = ((unsigned)(kt * 64 + quad * 16)) ^ swl;
        short8 x0 = *(const short8*)(&smem[(unsigned)(     l15) * 1024 + bo]);
        short8 x1 = *(const short8*)(&smem[(unsigned)(16 + l15) * 1024 + bo]);
        short8 x2 = *(const short8*)(&smem[(unsigned)(32 + l15) * 1024 + bo]);
        short8 x3 = *(const short8*)(&smem[(unsigned)(48 + l15) * 1024 + bo]);
        ac0 = __builtin_amdgcn_mfma_f32_16x16x32_bf16(wf, x0, ac0, 0, 0, 0);
        ac1 = __builtin_amdgcn_mfma_f32_16x16x32_bf16(wf, x1, ac1, 0, 0, 0);
        ac2 = __builtin_amdgcn_mfma_f32_16x16x32_bf16(wf, x2, ac2, 0, 0, 0);
        ac3 = __builtin_amdgcn_mfma_f32_16x16x32_bf16(wf, x3, ac3, 0, 0, 0);
    }

#define EPI(AC, S) do {                                                             \
    int row = rowb + (S) * 16 + l15;                                                \
    if (row < N) {                                                                  \
        uint2 ix = *(const uint2*)(xb + (size_t)row * DIM + colb);                  \
        float4 o;                                                                   \
        o.x = (AC)[0] + bf2f(ix.x & 0xffffu);                                       \
        o.y = (AC)[1] + bf2f(ix.x >> 16);                                           \
        o.z = (AC)[2] + bf2f(ix.y & 0xffffu);                                       \
        o.w = (AC)[3] + bf2f(ix.y >> 16);                                           \
        if (!bz) {                                                                  \
            float4 sb = *(const float4*)(Sb + (size_t)row * DIM + colb);            \
            o.x += sb.x; o.y += sb.y; o.z += sb.z; o.w += sb.w;                     \
        }                                                                           \
        o.x = fmaxf(o.x, 0.f); o.y = fmaxf(o.y, 0.f);                               \
        o.z = fmaxf(o.z, 0.f); o.w = fmaxf(o.w, 0.f);                               \
        *(float4*)(out + (size_t)row * DIM + colb) = o;                             \
    }                                                                               \
} while (0)

    EPI(ac0, 0);
    EPI(ac1, 1);
    EPI(ac2, 2);
    EPI(ac3, 3);
#undef EPI
}

extern "C" void kernel_launch(void* const* d_in, const int* in_sizes, int n_in,
                              void* d_out, int out_size, void* d_ws, size_t ws_size,
                              hipStream_t stream)
{
    const float* inp    = (const float*)d_in[0];
    const int*   deprel = (const int*)d_in[1];
    const int*   deparc = (const int*)d_in[2];
    const int*   ei     = (const int*)d_in[3];
    const float* Vin    = (const float*)d_in[4];
    const float* b_in   = (const float*)d_in[5];
    const float* gin    = (const float*)d_in[6];
    const float* bg_in  = (const float*)d_in[7];
    const float* Vout   = (const float*)d_in[8];
    const float* b_out  = (const float*)d_in[9];
    const float* gout   = (const float*)d_in[10];
    const float* bg_out = (const float*)d_in[11];
    const float* Wself  = (const float*)d_in[12];
    const float* gself  = (const float*)d_in[13];
    const float* Wnorel = (const float*)d_in[14];
    const float* gnorel = (const float*)d_in[15];
    float*       out    = (float*)d_out;

    const int N = in_sizes[0] / DIM;   // 100000
    const int E = in_sizes[1];         // 400000
    const long long nbe = (long long)in_sizes[5];  // R*128

    char* ws = (char*)d_ws;
    size_t off = 0;
    auto alloc = [&](size_t bytes) -> void* {
        void* p = ws + off;
        off = (off + bytes + 255) & ~(size_t)255;
        return p;
    };
    float*          xg        = (float*)alloc((size_t)N * 4 * 4);
    int*            counts    = (int*)alloc((size_t)N * 4);   // |
    int*            bnz       = (int*)alloc(256);             // | one memset region
    int*            flags     = (int*)alloc(512);             // | (scan lookback)
    int*            row_start = (int*)alloc((size_t)N * 4);
    int*            cursor    = (int*)alloc((size_t)N * 4);
    int2*           pe2       = (int2*)alloc((size_t)E * 8);
    int*            rel_arr   = (int*)alloc((size_t)E * 4);
    unsigned short* xb        = (unsigned short*)alloc((size_t)N * DIM * 2); // 25.6 MB
    unsigned short* wcatT     = (unsigned short*)alloc((size_t)128 * 512 * 2); // 128 KB
    float*          Sb        = (float*)alloc((size_t)N * DIM * 4);          // 51.2 MB

    int nb_scan  = (N + 1023) / 1024;   // 98 blocks, all co-resident
    int nb_edge  = (E + 255) / 256;
    int nb_node  = (N + 63) / 64;
    int nb_fused = (N + 63) / 64;

    // zero counts + bnz + flags in one memset (adjacent in ws)
    size_t zlen = (size_t)((char*)flags - (char*)counts) + 512;
    hipMemsetAsync(counts, 0, zlen, stream);

    conv_hist_k<<<nb_node + nb_edge + 256 + 128, 256, 0, stream>>>(
        inp, gin, gout, gself, gnorel, Vin, Vout, Wself, Wnorel,
        xb, xg, wcatT, ei, counts, b_in, b_out, bnz, nbe, N, E, nb_node, nb_edge);

    scan_onepass_k<<<nb_scan, 256, 0, stream>>>(counts, row_start, cursor, flags, N);

    scatter_payload_k<<<nb_edge, 256, 0, stream>>>(ei, deprel, deparc, cursor,
                                                   xg, bg_in, bg_out, pe2, rel_arr, bnz, E);

    fused_agg_gemm_k<<<nb_fused, 512, 0, stream>>>(
        xb, wcatT, pe2, rel_arr, row_start, counts, b_in, b_out, Sb, out, bnz, N);
}